// Round 4
// baseline (336.091 us; speedup 1.0000x reference)
//
#include <hip/hip_runtime.h>
#include <math.h>

#define NL  1024     // N_LEVELS
#define KP1 9        // K+1
#define NB  2048     // direct-mapped buckets (2048*16B = 32 KB LDS)

// d_ws float layout:
//   [0]=lo0 [1]=inv [2..3] pad
//   [WS_TAB .. +1024)   out-value table per level
//   [WS_BS  .. +1032)   1023 fp32 decision boundaries + 9 INF pads
//   [WS_REC .. +8192)   2048 x float4 records {S, vL, vR, aux}
#define WS_TAB 4
#define WS_BS  1028
#define WS_REC 2064   // float index; byte 8256 (16B aligned); total ws ~41 KB

// native 4-wide float vector (works with __builtin_nontemporal_*)
typedef float f32x4 __attribute__((ext_vector_type(4)));

// order-preserving float<->uint map (total order incl. negatives)
__device__ __forceinline__ unsigned oi(float f) {
    unsigned u = __float_as_uint(f);
    return (u & 0x80000000u) ? ~u : (u | 0x80000000u);
}
__device__ __forceinline__ float unoi(unsigned k) {
    return __uint_as_float((k & 0x80000000u) ? (k & 0x7fffffffu) : ~k);
}

// bucket index — MUST be the identical fp32 op sequence in build and main
// kernels (fp sub / mul-by-positive / trunc / clamp are all monotone).
__device__ __forceinline__ int bidx(float x, float lo0, float inv) {
    float t = (x - lo0) * inv;
    int j = (int)t;
    j = j < 0 ? 0 : j;
    j = j > (NB - 1) ? (NB - 1) : j;
    return j;
}

// ---------------------------------------------------------------------------
// Build kernel (1 block, 1024 threads):
//  1. tab[i] = reference threshold-chain output for level i (exact replica)
//  2. B[i]   = smallest fp32 x where pair (i,i+1) chooses RIGHT (bit-level
//              binary search of the exact reference predicate)
//  3. per-bucket record {S, vL, vR, aux}:
//       cnt==0: S=+INF, vL=vR=tab[s]
//       cnt==1: S=B[s], vL=tab[s], vR=tab[s+1]
//       cnt>=2: aux = 0x80000000|s  -> escape scan in main kernel
//     where s = #{boundaries in buckets < j}
// ---------------------------------------------------------------------------
__global__ __launch_bounds__(1024) void build_kernel(
    const float* __restrict__ h, const float* __restrict__ d,
    const float* __restrict__ T, const float* __restrict__ bp,
    float* __restrict__ ws)
{
    __shared__ float s_g[NL];
    __shared__ float s_B[NL];     // 1023 boundaries + [1023]=INF
    __shared__ float s_tab[NL];
    __shared__ int   s_jb[NL];    // bidx of each boundary + INT_MAX sentinel
    __shared__ float s_lo0, s_inv;

    const int tid = threadIdx.x;
    float g = h[tid * KP1];
    s_g[tid] = g;

    // 1. out-value table (exact replica of reference fp32 sequence)
    {
        float v = g, outv = 0.0f, b = bp[0];
#pragma unroll
        for (int t = 1; t <= 8; ++t) {
            float z = ((v - T[t]) >= 0.0f) ? 1.0f : 0.0f;
            outv = outv + z * d[t];
            if (t != 8) v = h[tid * KP1 + (t + 1)];
        }
        float tv = outv - b;
        s_tab[tid] = tv;
        ws[WS_TAB + tid] = tv;
    }
    __syncthreads();

    // 2. exact fp32 decision boundary per adjacent pair
    if (tid < NL - 1) {
        float l = s_g[tid], r = s_g[tid + 1];
        unsigned a = oi(l), b2 = oi(r);   // predicate false at l, true at r
        while (a < b2) {
            unsigned m = a + ((b2 - a) >> 1);
            float xm = unoi(m);
            float dl = fabsf(xm - l), dr = fabsf(xm - r);
            if (!(dl < dr)) b2 = m; else a = m + 1;
        }
        s_B[tid] = unoi(a);
    } else {
        s_B[tid] = INFINITY;
    }
    __syncthreads();

    if (tid == 0) {
        float lo0 = s_B[0];
        float inv = (float)NB / (s_B[NL - 2] - lo0);
        s_lo0 = lo0; s_inv = inv;
        ws[0] = lo0; ws[1] = inv;
    }
    __syncthreads();

    float lo0 = s_lo0, inv = s_inv;
    s_jb[tid] = (tid < NL - 1) ? bidx(s_B[tid], lo0, inv) : 0x7fffffff;
    ws[WS_BS + tid] = s_B[tid];                       // [1023] = INF
    if (tid < 8) ws[WS_BS + NL + tid] = INFINITY;     // escape-scan pads
    __syncthreads();

    // 3. per-bucket records (lower_bound over sorted s_jb, 1024 entries)
    float4* rec = (float4*)(ws + WS_REC);
    for (int j = tid; j < NB; j += 1024) {
        int s0 = 0, s1 = 0;
#pragma unroll
        for (int s = 512; s >= 1; s >>= 1)
            if (s_jb[s0 + s - 1] < j) s0 += s;
#pragma unroll
        for (int s = 512; s >= 1; s >>= 1)
            if (s_jb[s1 + s - 1] < j + 1) s1 += s;
        int cnt = s1 - s0;
        float S, vL, vR; unsigned aux = 0u;
        if (cnt == 0)      { S = INFINITY; vL = s_tab[s0]; vR = vL; }
        else if (cnt == 1) { S = s_B[s0];  vL = s_tab[s0]; vR = s_tab[s0 + 1]; }
        else               { S = 0.0f; vL = 0.0f; vR = 0.0f;
                             aux = 0x80000000u | (unsigned)s0; }
        rec[j] = make_float4(S, vL, vR, __uint_as_float(aux));
    }
}

// ---------------------------------------------------------------------------
// Main kernel: per element — ONE ds_read_b128 + select (common); rare escape
// scans the L2-resident global boundary/table arrays (~9% of lanes).
// ---------------------------------------------------------------------------
__global__ __launch_bounds__(256) void ps_act_kernel(
    const float* __restrict__ x,
    const float* __restrict__ ws,
    float* __restrict__ out,
    int n4)
{
    __shared__ float4 srec[NB];   // exactly 32 KB -> 5 blocks/CU

    const int tid = threadIdx.x;
    const float4* grec = (const float4*)(ws + WS_REC);
    for (int i = tid; i < NB; i += 256) srec[i] = grec[i];
    const float lo0 = ws[0];
    const float inv = ws[1];
    const float* __restrict__ gB   = ws + WS_BS;
    const float* __restrict__ gtab = ws + WS_TAB;
    __syncthreads();

    const f32x4* __restrict__ x4 = (const f32x4*)x;
    f32x4* __restrict__ o4 = (f32x4*)out;
    const int stride = gridDim.x * blockDim.x;

    for (int i4 = blockIdx.x * blockDim.x + tid; i4 < n4; i4 += stride) {
        f32x4 xv = __builtin_nontemporal_load(&x4[i4]);
        float xo[4];
#pragma unroll
        for (int e = 0; e < 4; ++e) {
            float xf = xv[e];
            int j = bidx(xf, lo0, inv);
            float4 q = srec[j];
            float r = (xf >= q.x) ? q.z : q.y;
            unsigned a = __float_as_uint(q.w);
            if (a) {                       // cnt>=2 bucket: rare scan
                int ni = (int)(a & 0x7fffffffu);
                while (gB[ni] <= xf) ++ni; // INF pads guarantee termination
                r = gtab[ni];
            }
            xo[e] = r;
        }
        f32x4 ov = {xo[0], xo[1], xo[2], xo[3]};
        __builtin_nontemporal_store(ov, &o4[i4]);
    }
}

extern "C" void kernel_launch(void* const* d_in, const int* in_sizes, int n_in,
                              void* d_out, int out_size, void* d_ws, size_t ws_size,
                              hipStream_t stream) {
    const float* x = (const float*)d_in[0];
    const float* h = (const float*)d_in[1];
    const float* d = (const float*)d_in[2];
    const float* T = (const float*)d_in[3];
    const float* b = (const float*)d_in[4];
    float* out = (float*)d_out;
    float* ws  = (float*)d_ws;

    int n  = in_sizes[0];
    int n4 = n / 4;

    build_kernel<<<1, 1024, 0, stream>>>(h, d, T, b, ws);
    // 1024 blocks x 256: all resident in one round (5 blocks/CU at 32 KB LDS),
    // 64 float4 iterations/thread amortizes the 32 KB LDS staging.
    ps_act_kernel<<<1024, 256, 0, stream>>>(x, ws, out, n4);
}

// Round 5
// 261.957 us; speedup vs baseline: 1.2830x; 1.2830x over previous
//
#include <hip/hip_runtime.h>
#include <math.h>

#define NL  1024     // N_LEVELS
#define KP1 9        // K+1
#define NB  2048     // direct-mapped buckets (2048*16B = 32 KB LDS)

// d_ws float layout:
//   [0]=lo0 [1]=inv [2..3] pad
//   [WS_TAB .. +1024)   out-value table per level
//   [WS_BS  .. +1032)   1023 fp32 decision boundaries + 9 INF pads
//   [WS_REC .. +8192)   2048 x float4 records
#define WS_TAB 4
#define WS_BS  1028
#define WS_REC 2064   // float index; byte 8256 (16B aligned)

// native 4-wide float vector
typedef float f32x4 __attribute__((ext_vector_type(4)));

// order-preserving float<->uint map (total order incl. negatives)
__device__ __forceinline__ unsigned oi(float f) {
    unsigned u = __float_as_uint(f);
    return (u & 0x80000000u) ? ~u : (u | 0x80000000u);
}
__device__ __forceinline__ float unoi(unsigned k) {
    return __uint_as_float((k & 0x80000000u) ? (k & 0x7fffffffu) : ~k);
}

// bucket index — identical fp32 op sequence in build and main kernels
// (fp sub / mul-by-positive / trunc / clamp are all monotone).
__device__ __forceinline__ int bidx(float x, float lo0, float inv) {
    float t = (x - lo0) * inv;
    int j = (int)t;
    j = j < 0 ? 0 : j;
    j = j > (NB - 1) ? (NB - 1) : j;
    return j;
}

// ---------------------------------------------------------------------------
// Build kernel (1 block, 1024 threads). Record types by in-bucket boundary
// count (s0 = #{boundaries in buckets < j}):
//   cnt==0: {S=+INF, vL=tab[s0], vR=vL, aux=0}          -> 1-hop select
//   cnt==1: {S=B[s0], vL=tab[s0], vR=tab[s0+1], aux=0}  -> 1-hop select
//   cnt 2-3: {b0,b1,b2(INF pad), aux=0x8000_0000|s0}    -> probes + stab hop
//   cnt >3: {aux=0xC000_0000|s0}                        -> rare global scan
// ---------------------------------------------------------------------------
__global__ __launch_bounds__(1024) void build_kernel(
    const float* __restrict__ h, const float* __restrict__ d,
    const float* __restrict__ T, const float* __restrict__ bp,
    float* __restrict__ ws)
{
    __shared__ float s_g[NL];
    __shared__ float s_B[NL];     // 1023 boundaries + [1023]=INF
    __shared__ float s_tab[NL];
    __shared__ int   s_jb[NL];    // bidx of each boundary + INT_MAX sentinel
    __shared__ float s_lo0, s_inv;

    const int tid = threadIdx.x;
    float g = h[tid * KP1];
    s_g[tid] = g;

    // 1. out-value table (exact replica of reference fp32 sequence)
    {
        float v = g, outv = 0.0f, b = bp[0];
#pragma unroll
        for (int t = 1; t <= 8; ++t) {
            float z = ((v - T[t]) >= 0.0f) ? 1.0f : 0.0f;
            outv = outv + z * d[t];
            if (t != 8) v = h[tid * KP1 + (t + 1)];
        }
        float tv = outv - b;
        s_tab[tid] = tv;
        ws[WS_TAB + tid] = tv;
    }
    __syncthreads();

    // 2. exact fp32 decision boundary per adjacent pair (bit-level search of
    //    the exact reference predicate !(|x-l|<|x-r|))
    if (tid < NL - 1) {
        float l = s_g[tid], r = s_g[tid + 1];
        unsigned a = oi(l), b2 = oi(r);   // predicate false at l, true at r
        while (a < b2) {
            unsigned m = a + ((b2 - a) >> 1);
            float xm = unoi(m);
            float dl = fabsf(xm - l), dr = fabsf(xm - r);
            if (!(dl < dr)) b2 = m; else a = m + 1;
        }
        s_B[tid] = unoi(a);
    } else {
        s_B[tid] = INFINITY;
    }
    __syncthreads();

    if (tid == 0) {
        float lo0 = s_B[0];
        float inv = (float)NB / (s_B[NL - 2] - lo0);
        s_lo0 = lo0; s_inv = inv;
        ws[0] = lo0; ws[1] = inv;
    }
    __syncthreads();

    float lo0 = s_lo0, inv = s_inv;
    s_jb[tid] = (tid < NL - 1) ? bidx(s_B[tid], lo0, inv) : 0x7fffffff;
    ws[WS_BS + tid] = s_B[tid];                       // [1023] = INF
    if (tid < 8) ws[WS_BS + NL + tid] = INFINITY;     // escape-scan pads
    __syncthreads();

    // 3. per-bucket records (lower_bound over sorted s_jb)
    float4* rec = (float4*)(ws + WS_REC);
    for (int j = tid; j < NB; j += 1024) {
        int s0 = 0, s1 = 0;
#pragma unroll
        for (int s = 512; s >= 1; s >>= 1)
            if (s_jb[s0 + s - 1] < j) s0 += s;
#pragma unroll
        for (int s = 512; s >= 1; s >>= 1)
            if (s_jb[s1 + s - 1] < j + 1) s1 += s;
        int cnt = s1 - s0;
        float X, Y, Z; unsigned aux;
        if (cnt == 0) {
            X = INFINITY; Y = s_tab[s0]; Z = Y; aux = 0u;
        } else if (cnt == 1) {
            X = s_B[s0]; Y = s_tab[s0]; Z = s_tab[s0 + 1]; aux = 0u;
        } else if (cnt <= 3) {
            X = s_B[s0]; Y = s_B[s0 + 1];
            Z = (cnt == 3) ? s_B[s0 + 2] : INFINITY;
            aux = 0x80000000u | (unsigned)s0;
        } else {
            X = 0.0f; Y = 0.0f; Z = 0.0f;
            aux = 0xC0000000u | (unsigned)s0;
        }
        rec[j] = make_float4(X, Y, Z, __uint_as_float(aux));
    }
}

// ---------------------------------------------------------------------------
// Main kernel lookup: 1 ds_read_b128 (all); +1 LDS stab read for ~9%;
// global scan only for cnt>3 buckets (~0.2% of elements).
// ---------------------------------------------------------------------------
__device__ __forceinline__ float lookup(float xf,
                                        const float4* __restrict__ srec,
                                        const float* __restrict__ stab,
                                        const float* __restrict__ gB,
                                        float lo0, float inv)
{
    int j = bidx(xf, lo0, inv);
    float4 q = srec[j];
    unsigned a = __float_as_uint(q.w);
    float r = (xf >= q.x) ? q.z : q.y;     // valid when aux==0
    if (a) {
        int ni = (int)(a & 0xFFFFu);
        if (a & 0x40000000u) {             // cnt>3: rare global scan
            while (gB[ni] <= xf) ++ni;     // INF pads guarantee termination
        } else {                           // cnt 2-3: branchless probes
            ni += (q.x <= xf) + (q.y <= xf) + (q.z <= xf);
        }
        r = stab[ni];
    }
    return r;
}

__global__ __launch_bounds__(256) void ps_act_kernel(
    const float* __restrict__ x,
    const float* __restrict__ ws,
    float* __restrict__ out,
    int n4)
{
    __shared__ float4 srec[NB];   // 32 KB
    __shared__ float  stab[NL];   // 4 KB  -> total 36 KB, 4 blocks/CU

    const int tid = threadIdx.x;
    const float4* grec = (const float4*)(ws + WS_REC);
    for (int i = tid; i < NB; i += 256) srec[i] = grec[i];
    for (int i = tid; i < NL; i += 256) stab[i] = ws[WS_TAB + i];
    const float lo0 = ws[0];
    const float inv = ws[1];
    const float* __restrict__ gB = ws + WS_BS;
    __syncthreads();

    const f32x4* __restrict__ x4 = (const f32x4*)x;
    f32x4* __restrict__ o4 = (f32x4*)out;
    const int stride = gridDim.x * blockDim.x;

    int i4 = blockIdx.x * blockDim.x + tid;
    // unroll-2: two independent global-load -> LDS -> store chains in flight
    for (; i4 + stride < n4; i4 += 2 * stride) {
        f32x4 xa = x4[i4];
        f32x4 xb = x4[i4 + stride];
        f32x4 oa, ob;
#pragma unroll
        for (int e = 0; e < 4; ++e) {
            oa[e] = lookup(xa[e], srec, stab, gB, lo0, inv);
            ob[e] = lookup(xb[e], srec, stab, gB, lo0, inv);
        }
        o4[i4] = oa;
        o4[i4 + stride] = ob;
    }
    for (; i4 < n4; i4 += stride) {
        f32x4 xa = x4[i4];
        f32x4 oa;
#pragma unroll
        for (int e = 0; e < 4; ++e)
            oa[e] = lookup(xa[e], srec, stab, gB, lo0, inv);
        o4[i4] = oa;
    }
}

extern "C" void kernel_launch(void* const* d_in, const int* in_sizes, int n_in,
                              void* d_out, int out_size, void* d_ws, size_t ws_size,
                              hipStream_t stream) {
    const float* x = (const float*)d_in[0];
    const float* h = (const float*)d_in[1];
    const float* d = (const float*)d_in[2];
    const float* T = (const float*)d_in[3];
    const float* b = (const float*)d_in[4];
    float* out = (float*)d_out;
    float* ws  = (float*)d_ws;

    int n  = in_sizes[0];
    int n4 = n / 4;

    build_kernel<<<1, 1024, 0, stream>>>(h, d, T, b, ws);
    // 2048 blocks x 256: 8 blocks/CU queued (4 resident at 36 KB LDS),
    // 16 f32x4 per thread = 8 unroll-2 iterations.
    ps_act_kernel<<<2048, 256, 0, stream>>>(x, ws, out, n4);
}

// Round 6
// 259.849 us; speedup vs baseline: 1.2934x; 1.0081x over previous
//
#include <hip/hip_runtime.h>
#include <math.h>

#define NL  1024     // N_LEVELS
#define KP1 9        // K+1
#define NB  2048     // direct-mapped buckets (2048*16B = 32 KB LDS)

// d_ws float layout:
//   [0]=lo0 [1]=inv [2..3] pad
//   [WS_TAB .. +1024)   out-value table per level
//   [WS_BS  .. +1032)   1023 fp32 decision boundaries + 9 INF pads
//   [WS_REC .. +8192)   2048 x float4 records
#define WS_TAB 4
#define WS_BS  1028
#define WS_REC 2064   // float index; byte 8256 (16B aligned)

// native 4-wide float vector
typedef float f32x4 __attribute__((ext_vector_type(4)));

// order-preserving float<->uint map (total order incl. negatives)
__device__ __forceinline__ unsigned oi(float f) {
    unsigned u = __float_as_uint(f);
    return (u & 0x80000000u) ? ~u : (u | 0x80000000u);
}
__device__ __forceinline__ float unoi(unsigned k) {
    return __uint_as_float((k & 0x80000000u) ? (k & 0x7fffffffu) : ~k);
}

// bucket index — identical fp32 op sequence in build and main kernels
// (fp sub / mul-by-positive / trunc / clamp are all monotone).
__device__ __forceinline__ int bidx(float x, float lo0, float inv) {
    float t = (x - lo0) * inv;
    int j = (int)t;
    j = j < 0 ? 0 : j;
    j = j > (NB - 1) ? (NB - 1) : j;
    return j;
}

// ---------------------------------------------------------------------------
// Build kernel (1 block, 1024 threads). Record types by in-bucket boundary
// count (s0 = #{boundaries in buckets < j}):
//   cnt==0: {S=+INF, vL=tab[s0], vR=vL, aux=0}          -> 1-hop select
//   cnt==1: {S=B[s0], vL=tab[s0], vR=tab[s0+1], aux=0}  -> 1-hop select
//   cnt 2-3: {b0,b1,b2(INF pad), aux=0x8000_0000|s0}    -> probes + stab hop
//   cnt >3: {aux=0xC000_0000|s0}                        -> rare global scan
// ---------------------------------------------------------------------------
__global__ __launch_bounds__(1024) void build_kernel(
    const float* __restrict__ h, const float* __restrict__ d,
    const float* __restrict__ T, const float* __restrict__ bp,
    float* __restrict__ ws)
{
    __shared__ float s_g[NL];
    __shared__ float s_B[NL];     // 1023 boundaries + [1023]=INF
    __shared__ float s_tab[NL];
    __shared__ int   s_jb[NL];    // bidx of each boundary + INT_MAX sentinel
    __shared__ float s_lo0, s_inv;

    const int tid = threadIdx.x;
    float g = h[tid * KP1];
    s_g[tid] = g;

    // 1. out-value table (exact replica of reference fp32 sequence)
    {
        float v = g, outv = 0.0f, b = bp[0];
#pragma unroll
        for (int t = 1; t <= 8; ++t) {
            float z = ((v - T[t]) >= 0.0f) ? 1.0f : 0.0f;
            outv = outv + z * d[t];
            if (t != 8) v = h[tid * KP1 + (t + 1)];
        }
        float tv = outv - b;
        s_tab[tid] = tv;
        ws[WS_TAB + tid] = tv;
    }
    __syncthreads();

    // 2. exact fp32 decision boundary per adjacent pair (bit-level search of
    //    the exact reference predicate !(|x-l|<|x-r|))
    if (tid < NL - 1) {
        float l = s_g[tid], r = s_g[tid + 1];
        unsigned a = oi(l), b2 = oi(r);   // predicate false at l, true at r
        while (a < b2) {
            unsigned m = a + ((b2 - a) >> 1);
            float xm = unoi(m);
            float dl = fabsf(xm - l), dr = fabsf(xm - r);
            if (!(dl < dr)) b2 = m; else a = m + 1;
        }
        s_B[tid] = unoi(a);
    } else {
        s_B[tid] = INFINITY;
    }
    __syncthreads();

    if (tid == 0) {
        float lo0 = s_B[0];
        float inv = (float)NB / (s_B[NL - 2] - lo0);
        s_lo0 = lo0; s_inv = inv;
        ws[0] = lo0; ws[1] = inv;
    }
    __syncthreads();

    float lo0 = s_lo0, inv = s_inv;
    s_jb[tid] = (tid < NL - 1) ? bidx(s_B[tid], lo0, inv) : 0x7fffffff;
    ws[WS_BS + tid] = s_B[tid];                       // [1023] = INF
    if (tid < 8) ws[WS_BS + NL + tid] = INFINITY;     // escape-scan pads
    __syncthreads();

    // 3. per-bucket records (lower_bound over sorted s_jb)
    float4* rec = (float4*)(ws + WS_REC);
    for (int j = tid; j < NB; j += 1024) {
        int s0 = 0, s1 = 0;
#pragma unroll
        for (int s = 512; s >= 1; s >>= 1)
            if (s_jb[s0 + s - 1] < j) s0 += s;
#pragma unroll
        for (int s = 512; s >= 1; s >>= 1)
            if (s_jb[s1 + s - 1] < j + 1) s1 += s;
        int cnt = s1 - s0;
        float X, Y, Z; unsigned aux;
        if (cnt == 0) {
            X = INFINITY; Y = s_tab[s0]; Z = Y; aux = 0u;
        } else if (cnt == 1) {
            X = s_B[s0]; Y = s_tab[s0]; Z = s_tab[s0 + 1]; aux = 0u;
        } else if (cnt <= 3) {
            X = s_B[s0]; Y = s_B[s0 + 1];
            Z = (cnt == 3) ? s_B[s0 + 2] : INFINITY;
            aux = 0x80000000u | (unsigned)s0;
        } else {
            X = 0.0f; Y = 0.0f; Z = 0.0f;
            aux = 0xC0000000u | (unsigned)s0;
        }
        rec[j] = make_float4(X, Y, Z, __uint_as_float(aux));
    }
}

// ---------------------------------------------------------------------------
// Main kernel lookup: 1 ds_read_b128 (all); +1 LDS stab read for ~9%;
// global scan only for cnt>3 buckets (~0.2% of elements).
// ---------------------------------------------------------------------------
__device__ __forceinline__ float lookup(float xf,
                                        const float4* __restrict__ srec,
                                        const float* __restrict__ stab,
                                        const float* __restrict__ gB,
                                        float lo0, float inv)
{
    int j = bidx(xf, lo0, inv);
    float4 q = srec[j];
    unsigned a = __float_as_uint(q.w);
    float r = (xf >= q.x) ? q.z : q.y;     // valid when aux==0
    if (a) {
        int ni = (int)(a & 0xFFFFu);
        if (a & 0x40000000u) {             // cnt>3: rare global scan
            while (gB[ni] <= xf) ++ni;     // INF pads guarantee termination
        } else {                           // cnt 2-3: branchless probes
            ni += (q.x <= xf) + (q.y <= xf) + (q.z <= xf);
        }
        r = stab[ni];
    }
    return r;
}

__global__ __launch_bounds__(256) void ps_act_kernel(
    const float* __restrict__ x,
    const float* __restrict__ ws,
    float* __restrict__ out,
    int n4)
{
    __shared__ float4 srec[NB];   // 32 KB
    __shared__ float  stab[NL];   // 4 KB  -> total 36 KB, 4 blocks/CU

    const int tid = threadIdx.x;
    const float4* grec = (const float4*)(ws + WS_REC);
    for (int i = tid; i < NB; i += 256) srec[i] = grec[i];
    for (int i = tid; i < NL; i += 256) stab[i] = ws[WS_TAB + i];
    const float lo0 = ws[0];
    const float inv = ws[1];
    const float* __restrict__ gB = ws + WS_BS;
    __syncthreads();

    const f32x4* __restrict__ x4 = (const f32x4*)x;
    f32x4* __restrict__ o4 = (f32x4*)out;
    const int stride = gridDim.x * blockDim.x;

    int i4 = blockIdx.x * blockDim.x + tid;
    // unroll-4: four independent global-load -> LDS -> store chains in
    // flight per wave. Little's law: 4 waves/SIMD x 4 x 1 KB = 16 KB
    // in-flight > ~9.2 KB needed to sustain 6.3 TB/s at ~900 cyc latency.
    for (; i4 + 3 * stride < n4; i4 += 4 * stride) {
        f32x4 xa = x4[i4];
        f32x4 xb = x4[i4 + stride];
        f32x4 xc = x4[i4 + 2 * stride];
        f32x4 xd = x4[i4 + 3 * stride];
        f32x4 oa, ob, oc, od;
#pragma unroll
        for (int e = 0; e < 4; ++e) {
            oa[e] = lookup(xa[e], srec, stab, gB, lo0, inv);
            ob[e] = lookup(xb[e], srec, stab, gB, lo0, inv);
            oc[e] = lookup(xc[e], srec, stab, gB, lo0, inv);
            od[e] = lookup(xd[e], srec, stab, gB, lo0, inv);
        }
        o4[i4] = oa;
        o4[i4 + stride] = ob;
        o4[i4 + 2 * stride] = oc;
        o4[i4 + 3 * stride] = od;
    }
    for (; i4 < n4; i4 += stride) {
        f32x4 xa = x4[i4];
        f32x4 oa;
#pragma unroll
        for (int e = 0; e < 4; ++e)
            oa[e] = lookup(xa[e], srec, stab, gB, lo0, inv);
        o4[i4] = oa;
    }
}

extern "C" void kernel_launch(void* const* d_in, const int* in_sizes, int n_in,
                              void* d_out, int out_size, void* d_ws, size_t ws_size,
                              hipStream_t stream) {
    const float* x = (const float*)d_in[0];
    const float* h = (const float*)d_in[1];
    const float* d = (const float*)d_in[2];
    const float* T = (const float*)d_in[3];
    const float* b = (const float*)d_in[4];
    float* out = (float*)d_out;
    float* ws  = (float*)d_ws;

    int n  = in_sizes[0];
    int n4 = n / 4;

    build_kernel<<<1, 1024, 0, stream>>>(h, d, T, b, ws);
    // 2048 blocks x 256: n4/threads = 16 -> exactly 4 unroll-4 iters/thread.
    ps_act_kernel<<<2048, 256, 0, stream>>>(x, ws, out, n4);
}